// Round 8
// baseline (90953.363 us; speedup 1.0000x reference)
//
#include <hip/hip_runtime.h>
#include <math.h>

// ---------------------------------------------------------------------------
// 2-layer LSTM, batch=1, T=32768, I=128, H=512  (PyTorch gate order i,f,g,o)
//
// 24 persistent WGs x 512 threads (grid == 24, 1 WG/CU).
//   WG 0..15  : layer-1, WG k owns h1[k*32 .. k*32+32)
//   WG 16..23 : layer-2, WG j owns h2[(j-16)*16 ..+16), runs 1 step behind.
//
// Handoff: (tag<<32)|f32bits u64 words in depth-8 rings, device-scope sc1
// stores/loads (proven rounds 2-3-6-7). Consumer's poll IS the data load.
// Per-lane early-exit: a lane that matched stages to LDS and stops loading.
// Overwrite guard (readers' tags >= n-3) in wave 3, every 4th step only.
// One __syncthreads per step; double-buffered LDS operand staging.
//
// KEY FIX THIS ROUND: all per-thread weights are PINNED into VGPRs with
// asm volatile("" : "+v"(w)) — rounds 2-7 reported VGPR_Count 68-108 with
// 80-160 declared weight floats, i.e. the compiler was REMATERIALIZING the
// weight loads from L2 inside the time loop (~327KB/WG/step), adding
// >1000cy of load latency to every step's compute phase.
// __launch_bounds__(512, 2) raises the allocator budget to 256 VGPRs.
// ---------------------------------------------------------------------------

#define T_STEPS 32768
#define L1WG    16
#define NWG     24
#define BLK     512
#define RD      8

// ws u32 layout
#define ABT_OFF  9
#define TAG_OFF  32                      // tags[24]
#define H1_OFF   1024                    // u64[RD][512] -> 8192 u32
#define H2_OFF   (H1_OFF + RD * 512 * 2) // u64[RD][128] -> 2048 u32
#define WS_WORDS (H2_OFF + RD * 128 * 2) // 11264 u32 = 45 KB

typedef unsigned int uint4v __attribute__((ext_vector_type(4)));

#define PIN(v) asm volatile("" : "+v"(v))

__device__ __forceinline__ float sigm(float x) { return 1.0f / (1.0f + __expf(-x)); }
__device__ __forceinline__ float tanh_fast(float x) { return 1.0f - 2.0f / (__expf(2.0f * x) + 1.0f); }

// ---- device-scope (sc1) access helpers -----------------------------------
__device__ __forceinline__ unsigned ld_u32_sc1(const unsigned* p) {
    unsigned r;
    asm volatile("global_load_dword %0, %1, off sc1\n\ts_waitcnt vmcnt(0)"
                 : "=v"(r) : "v"(p) : "memory");
    return r;
}
__device__ __forceinline__ void st_u32_sc1(unsigned* p, unsigned v) {
    asm volatile("global_store_dword %0, %1, off sc1" :: "v"(p), "v"(v) : "memory");
}
__device__ __forceinline__ void st_u64_sc1(unsigned long long* p, unsigned long long v) {
    asm volatile("global_store_dwordx2 %0, %1, off sc1" :: "v"(p), "v"(v) : "memory");
}
__device__ __forceinline__ void ld2x16_sc1(const unsigned long long* p, uint4v& A, uint4v& B) {
    asm volatile("global_load_dwordx4 %0, %2, off sc1\n\t"
                 "global_load_dwordx4 %1, %3, off sc1\n\t"
                 "s_waitcnt vmcnt(0)"
                 : "=&v"(A), "=&v"(B) : "v"(p), "v"(p + 2) : "memory");
}
__device__ __forceinline__ void ld1x16_sc1(const unsigned long long* p, uint4v& A) {
    asm volatile("global_load_dwordx4 %0, %1, off sc1\n\ts_waitcnt vmcnt(0)"
                 : "=&v"(A) : "v"(p) : "memory");
}

__global__ void lstm_init(unsigned int* ws)
{
    int i = blockIdx.x * blockDim.x + threadIdx.x;
    if (i < WS_WORDS) ws[i] = 0u;
}

__global__ __launch_bounds__(BLK, 2) void lstm_persist(
    const float* __restrict__ x,      // [32768][128]
    const float* __restrict__ Wih1,   // [2048][128]
    const float* __restrict__ Whh1,   // [2048][512]
    const float* __restrict__ bih1,
    const float* __restrict__ bhh1,
    const float* __restrict__ Wih2,   // [512][512]
    const float* __restrict__ Whh2,   // [512][128]
    const float* __restrict__ bih2,
    const float* __restrict__ bhh2,
    float* __restrict__ out,          // [32768][128]
    unsigned int* ws)
{
    const int role = blockIdx.x;      // 0..23
    const int tid  = threadIdx.x;
    const int wave = tid >> 6;
    const int lane = tid & 63;

    __shared__ __align__(16) float h1buf[2][16 * 36];   // chunked, stride 36
    __shared__ __align__(16) float h2buf[2][8 * 20];    // entry stride 20
    __shared__ unsigned s_ab[1];

    unsigned* abf  = ws + ABT_OFF;
    unsigned* tags = ws + TAG_OFF;
    unsigned long long* h1r = (unsigned long long*)(ws + H1_OFF);
    unsigned long long* h2r = (unsigned long long*)(ws + H2_OFF);

    if (tid == 0) s_ab[0] = 0u;

    const bool isL1 = role < L1WG;

    if (isL1) {
        // ================= LAYER 1: 32 h-indices per WG ====================
        const int rt = tid >> 4;          // 0..31 h-index
        const int ct = tid & 15;          // 0..15 col-tile (32 prim + 8 sec)
        const int hb = role * 32;

        float wA[4][32], wB[4][8], bia[4];
#pragma unroll
        for (int q = 0; q < 4; ++q) {
            const int grow = q * 512 + hb + rt;
            const float4* pa = (const float4*)(Whh1 + (size_t)grow * 512 + ct * 32);
#pragma unroll
            for (int c = 0; c < 8; ++c) {
                float4 f = pa[c];
                wA[q][c * 4 + 0] = f.x; wA[q][c * 4 + 1] = f.y;
                wA[q][c * 4 + 2] = f.z; wA[q][c * 4 + 3] = f.w;
            }
            const float4* pb = (const float4*)(Wih1 + (size_t)grow * 128 + ct * 8);
            float4 b0 = pb[0], b1 = pb[1];
            wB[q][0] = b0.x; wB[q][1] = b0.y; wB[q][2] = b0.z; wB[q][3] = b0.w;
            wB[q][4] = b1.x; wB[q][5] = b1.y; wB[q][6] = b1.z; wB[q][7] = b1.w;
            bia[q] = bih1[grow] + bhh1[grow];
        }
        // pin weights into VGPRs: non-rematerializable from here on
#pragma unroll
        for (int q = 0; q < 4; ++q) {
#pragma unroll
            for (int j = 0; j < 32; ++j) PIN(wA[q][j]);
#pragma unroll
            for (int j = 0; j < 8; ++j)  PIN(wB[q][j]);
            PIN(bia[q]);
        }

        float cst = 0.0f;
        float4 vx0 = *(const float4*)(x + ct * 8);
        float4 vx1 = *(const float4*)(x + ct * 8 + 4);
        __syncthreads();   // s_ab visible

        for (int n = 0; n < T_STEPS; ++n) {
            // ---- wave 3: overwrite guard, every 4th step, off crit path --
            if (wave == 3 && n >= 8 && (n & 3) == 0 && lane < NWG) {
                const int thr = n - 3;
                unsigned sp = 0;
                for (;;) {
                    int ok = ((int)ld_u32_sc1(&tags[lane]) >= thr);
                    if (__all(ok)) break;
                    if ((++sp & 255u) == 0u) {
                        if (ld_u32_sc1(abf) != 0u) { s_ab[0] = 1u; break; }
                        if (sp >= (1u << 21)) { st_u32_sc1(abf, 1u); s_ab[0] = 1u; break; }
                    }
                }
            }
            // ---- waves 0/1: poll+stage h1[n-1] (tag == n), early-exit ----
            if (wave < 2) {
                const size_t off = (size_t)((n - 1) & (RD - 1)) * 512 + wave * 256 + lane * 4;
                const unsigned long long* p = h1r + off;
                const unsigned e = (unsigned)n;
                const int g = wave * 256 + lane * 4;
                bool done = false;
                unsigned sp = 0;
                for (;;) {
                    if (!done) {
                        uint4v A, B;
                        ld2x16_sc1(p, A, B);
                        if ((A.y == e) & (A.w == e) & (B.y == e) & (B.w == e)) {
                            float4 vals = make_float4(
                                __uint_as_float(A.x), __uint_as_float(A.z),
                                __uint_as_float(B.x), __uint_as_float(B.z));
                            *(float4*)&h1buf[n & 1][(g >> 5) * 36 + (g & 31)] = vals;
                            done = true;
                        }
                    }
                    if (__all(done)) break;
                    if ((++sp & 255u) == 0u) {
                        if (ld_u32_sc1(abf) != 0u) { s_ab[0] = 1u; break; }
                        if (sp >= (1u << 21)) { st_u32_sc1(abf, 1u); s_ab[0] = 1u; break; }
                    }
                }
            }

            __syncthreads();
            if (s_ab[0]) break;
            if (tid == 0) st_u32_sc1(&tags[role], (unsigned)(n + 1));

            // ---- compute: 4 gates x (32 prim + 8 sec) cols ---------------
            float acc0 = 0.f, acc1 = 0.f, acc2 = 0.f, acc3 = 0.f;
            const float* hv = &h1buf[n & 1][ct * 36];
#pragma unroll
            for (int c = 0; c < 8; ++c) {
                float4 h4 = *(const float4*)(hv + c * 4);
                acc0 = fmaf(wA[0][c*4+0], h4.x, acc0); acc0 = fmaf(wA[0][c*4+1], h4.y, acc0);
                acc0 = fmaf(wA[0][c*4+2], h4.z, acc0); acc0 = fmaf(wA[0][c*4+3], h4.w, acc0);
                acc1 = fmaf(wA[1][c*4+0], h4.x, acc1); acc1 = fmaf(wA[1][c*4+1], h4.y, acc1);
                acc1 = fmaf(wA[1][c*4+2], h4.z, acc1); acc1 = fmaf(wA[1][c*4+3], h4.w, acc1);
                acc2 = fmaf(wA[2][c*4+0], h4.x, acc2); acc2 = fmaf(wA[2][c*4+1], h4.y, acc2);
                acc2 = fmaf(wA[2][c*4+2], h4.z, acc2); acc2 = fmaf(wA[2][c*4+3], h4.w, acc2);
                acc3 = fmaf(wA[3][c*4+0], h4.x, acc3); acc3 = fmaf(wA[3][c*4+1], h4.y, acc3);
                acc3 = fmaf(wA[3][c*4+2], h4.z, acc3); acc3 = fmaf(wA[3][c*4+3], h4.w, acc3);
            }
            {
                float sx[8] = { vx0.x, vx0.y, vx0.z, vx0.w, vx1.x, vx1.y, vx1.z, vx1.w };
#pragma unroll
                for (int j = 0; j < 8; ++j) {
                    acc0 = fmaf(wB[0][j], sx[j], acc0);
                    acc1 = fmaf(wB[1][j], sx[j], acc1);
                    acc2 = fmaf(wB[2][j], sx[j], acc2);
                    acc3 = fmaf(wB[3][j], sx[j], acc3);
                }
            }
            {   // prefetch next x row
                const int tn = (n + 1 < T_STEPS) ? (n + 1) : (T_STEPS - 1);
                vx0 = *(const float4*)(x + (size_t)tn * 128 + ct * 8);
                vx1 = *(const float4*)(x + (size_t)tn * 128 + ct * 8 + 4);
            }
#pragma unroll
            for (int m = 8; m >= 1; m >>= 1) {
                acc0 += __shfl_xor(acc0, m, 64);
                acc1 += __shfl_xor(acc1, m, 64);
                acc2 += __shfl_xor(acc2, m, 64);
                acc3 += __shfl_xor(acc3, m, 64);
            }
            const float ii = sigm(acc0 + bia[0]);
            const float ff = sigm(acc1 + bia[1]);
            const float g2 = tanh_fast(acc2 + bia[2]);
            const float oo = sigm(acc3 + bia[3]);
            cst = ff * cst + ii * g2;
            const float h = oo * tanh_fast(cst);

            if (ct == 0) {
                const unsigned long long pair =
                    ((unsigned long long)(unsigned)(n + 1) << 32) |
                    (unsigned long long)__float_as_uint(h);
                st_u64_sc1(&h1r[(size_t)(n & (RD - 1)) * 512 + hb + rt], pair);
            }
        }
    } else {
        // ================= LAYER 2: 16 h-indices per WG ====================
        const int rt  = tid >> 5;         // 0..15
        const int ct  = tid & 31;         // 0..31 (16 prim + 4 sec cols)
        const int hb2 = (role - L1WG) * 16;

        float wA[4][16], wB[4][4], bia[4];
#pragma unroll
        for (int q = 0; q < 4; ++q) {
            const int grow = q * 128 + hb2 + rt;
            const float4* pa = (const float4*)(Wih2 + (size_t)grow * 512 + ct * 16);
#pragma unroll
            for (int c = 0; c < 4; ++c) {
                float4 f = pa[c];
                wA[q][c * 4 + 0] = f.x; wA[q][c * 4 + 1] = f.y;
                wA[q][c * 4 + 2] = f.z; wA[q][c * 4 + 3] = f.w;
            }
            float4 b0 = *(const float4*)(Whh2 + (size_t)grow * 128 + ct * 4);
            wB[q][0] = b0.x; wB[q][1] = b0.y; wB[q][2] = b0.z; wB[q][3] = b0.w;
            bia[q] = bih2[grow] + bhh2[grow];
        }
#pragma unroll
        for (int q = 0; q < 4; ++q) {
#pragma unroll
            for (int j = 0; j < 16; ++j) PIN(wA[q][j]);
#pragma unroll
            for (int j = 0; j < 4; ++j)  PIN(wB[q][j]);
            PIN(bia[q]);
        }

        float cst = 0.0f;
        __syncthreads();   // s_ab visible

        for (int n = 1; n <= T_STEPS; ++n) {
            const int tau = n - 1;
            if (wave == 3 && n >= 8 && (n & 3) == 0 && lane < NWG) {
                const int thr = n - 3;
                unsigned sp = 0;
                for (;;) {
                    int ok = ((int)ld_u32_sc1(&tags[lane]) >= thr);
                    if (__all(ok)) break;
                    if ((++sp & 255u) == 0u) {
                        if (ld_u32_sc1(abf) != 0u) { s_ab[0] = 1u; break; }
                        if (sp >= (1u << 21)) { st_u32_sc1(abf, 1u); s_ab[0] = 1u; break; }
                    }
                }
            }
            // ---- waves 0/1: poll+stage h1[tau] (tag == n), early-exit ----
            if (wave < 2) {
                const size_t off = (size_t)(tau & (RD - 1)) * 512 + wave * 256 + lane * 4;
                const unsigned long long* p = h1r + off;
                const unsigned e = (unsigned)n;
                const int g = wave * 256 + lane * 4;
                bool done = false;
                unsigned sp = 0;
                for (;;) {
                    if (!done) {
                        uint4v A, B;
                        ld2x16_sc1(p, A, B);
                        if ((A.y == e) & (A.w == e) & (B.y == e) & (B.w == e)) {
                            float4 vals = make_float4(
                                __uint_as_float(A.x), __uint_as_float(A.z),
                                __uint_as_float(B.x), __uint_as_float(B.z));
                            *(float4*)&h1buf[n & 1][(g >> 5) * 36 + (g & 31)] = vals;
                            done = true;
                        }
                    }
                    if (__all(done)) break;
                    if ((++sp & 255u) == 0u) {
                        if (ld_u32_sc1(abf) != 0u) { s_ab[0] = 1u; break; }
                        if (sp >= (1u << 21)) { st_u32_sc1(abf, 1u); s_ab[0] = 1u; break; }
                    }
                }
            }
            // ---- wave 2: poll+stage h2[tau-1] (tag == tau), early-exit ---
            if (wave == 2) {
                const size_t off = (size_t)((tau - 1) & (RD - 1)) * 128 + lane * 2;
                const unsigned long long* p = h2r + off;
                const unsigned e = (unsigned)tau;
                const int pi = lane * 2;
                bool done = false;
                unsigned sp = 0;
                for (;;) {
                    if (!done) {
                        uint4v A;
                        ld1x16_sc1(p, A);
                        if ((A.y == e) & (A.w == e)) {
                            float2 v2 = make_float2(__uint_as_float(A.x),
                                                    __uint_as_float(A.z));
                            *(float2*)&h2buf[n & 1][(pi >> 4) * 20 + (pi & 15)] = v2;
                            done = true;
                        }
                    }
                    if (__all(done)) break;
                    if ((++sp & 255u) == 0u) {
                        if (ld_u32_sc1(abf) != 0u) { s_ab[0] = 1u; break; }
                        if (sp >= (1u << 21)) { st_u32_sc1(abf, 1u); s_ab[0] = 1u; break; }
                    }
                }
            }

            __syncthreads();
            if (s_ab[0]) break;
            if (tid == 0) st_u32_sc1(&tags[role], (unsigned)(n + 1));

            // ---- compute: 4 gates x (16 prim + 4 sec) --------------------
            float acc0 = 0.f, acc1 = 0.f, acc2 = 0.f, acc3 = 0.f;
            const float* hv = &h1buf[n & 1][(ct >> 1) * 36 + (ct & 1) * 16];
#pragma unroll
            for (int c = 0; c < 4; ++c) {
                float4 h4 = *(const float4*)(hv + c * 4);
                acc0 = fmaf(wA[0][c*4+0], h4.x, acc0); acc0 = fmaf(wA[0][c*4+1], h4.y, acc0);
                acc0 = fmaf(wA[0][c*4+2], h4.z, acc0); acc0 = fmaf(wA[0][c*4+3], h4.w, acc0);
                acc1 = fmaf(wA[1][c*4+0], h4.x, acc1); acc1 = fmaf(wA[1][c*4+1], h4.y, acc1);
                acc1 = fmaf(wA[1][c*4+2], h4.z, acc1); acc1 = fmaf(wA[1][c*4+3], h4.w, acc1);
                acc2 = fmaf(wA[2][c*4+0], h4.x, acc2); acc2 = fmaf(wA[2][c*4+1], h4.y, acc2);
                acc2 = fmaf(wA[2][c*4+2], h4.z, acc2); acc2 = fmaf(wA[2][c*4+3], h4.w, acc2);
                acc3 = fmaf(wA[3][c*4+0], h4.x, acc3); acc3 = fmaf(wA[3][c*4+1], h4.y, acc3);
                acc3 = fmaf(wA[3][c*4+2], h4.z, acc3); acc3 = fmaf(wA[3][c*4+3], h4.w, acc3);
            }
            {
                float4 s4 = *(const float4*)&h2buf[n & 1][(ct >> 2) * 20 + (ct & 3) * 4];
                float sv[4] = { s4.x, s4.y, s4.z, s4.w };
#pragma unroll
                for (int j = 0; j < 4; ++j) {
                    acc0 = fmaf(wB[0][j], sv[j], acc0);
                    acc1 = fmaf(wB[1][j], sv[j], acc1);
                    acc2 = fmaf(wB[2][j], sv[j], acc2);
                    acc3 = fmaf(wB[3][j], sv[j], acc3);
                }
            }
#pragma unroll
            for (int m = 16; m >= 1; m >>= 1) {
                acc0 += __shfl_xor(acc0, m, 64);
                acc1 += __shfl_xor(acc1, m, 64);
                acc2 += __shfl_xor(acc2, m, 64);
                acc3 += __shfl_xor(acc3, m, 64);
            }
            const float ii = sigm(acc0 + bia[0]);
            const float ff = sigm(acc1 + bia[1]);
            const float g2 = tanh_fast(acc2 + bia[2]);
            const float oo = sigm(acc3 + bia[3]);
            cst = ff * cst + ii * g2;
            const float h = oo * tanh_fast(cst);

            if (ct == 0) {
                const unsigned long long pair =
                    ((unsigned long long)(unsigned)n << 32) |
                    (unsigned long long)__float_as_uint(h);
                st_u64_sc1(&h2r[(size_t)(tau & (RD - 1)) * 128 + hb2 + rt], pair);
                out[(size_t)tau * 128 + hb2 + rt] = h;
            }
        }
    }
}

extern "C" void kernel_launch(void* const* d_in, const int* in_sizes, int n_in,
                              void* d_out, int out_size, void* d_ws, size_t ws_size,
                              hipStream_t stream)
{
    const float* x    = (const float*)d_in[0];
    const float* Wih1 = (const float*)d_in[1];
    const float* Whh1 = (const float*)d_in[2];
    const float* bih1 = (const float*)d_in[3];
    const float* bhh1 = (const float*)d_in[4];
    const float* Wih2 = (const float*)d_in[5];
    const float* Whh2 = (const float*)d_in[6];
    const float* bih2 = (const float*)d_in[7];
    const float* bhh2 = (const float*)d_in[8];
    unsigned int* ws  = (unsigned int*)d_ws;

    hipLaunchKernelGGL(lstm_init, dim3(44), dim3(256), 0, stream, ws);
    hipLaunchKernelGGL(lstm_persist, dim3(NWG), dim3(BLK), 0, stream,
                       x, Wih1, Whh1, bih1, bhh1, Wih2, Whh2, bih2, bhh2,
                       (float*)d_out, ws);
}